// Round 1
// baseline (1379.860 us; speedup 1.0000x reference)
//
#include <hip/hip_runtime.h>

// ---------------------------------------------------------------------------
// BlockGNN on MI355X, round 1: correct fp32 pipeline.
//   GCN trick: A_norm (X W) == (A_norm X) W  -> aggregate first, then GEMM.
//   Aggregation via CSR gather (no float atomics), self loop analytic.
// ---------------------------------------------------------------------------

__global__ void count_deg_kernel(const int* __restrict__ dst, int* __restrict__ deg, int E) {
  int e = blockIdx.x * blockDim.x + threadIdx.x;
  if (e < E) atomicAdd(&deg[dst[e]], 1);
}

__global__ void inv_s_kernel(const int* __restrict__ deg, float* __restrict__ inv_s, int N) {
  int i = blockIdx.x * blockDim.x + threadIdx.x;
  if (i < N) inv_s[i] = rsqrtf((float)(deg[i] + 1));  // +1 = self loop; always > 0
}

__global__ void scan_partial_kernel(const int* __restrict__ deg, int* __restrict__ bsum, int N) {
  __shared__ int s[256];
  int i = blockIdx.x * 256 + threadIdx.x;
  s[threadIdx.x] = (i < N) ? deg[i] : 0;
  __syncthreads();
  for (int off = 128; off > 0; off >>= 1) {
    if (threadIdx.x < off) s[threadIdx.x] += s[threadIdx.x + off];
    __syncthreads();
  }
  if (threadIdx.x == 0) bsum[blockIdx.x] = s[0];
}

__global__ void scan_block_kernel(const int* __restrict__ bsum, int* __restrict__ boff,
                                  int* __restrict__ row_off, int NB, int N) {
  __shared__ int s[256];
  int v = (threadIdx.x < NB) ? bsum[threadIdx.x] : 0;
  s[threadIdx.x] = v;
  __syncthreads();
  for (int off = 1; off < 256; off <<= 1) {
    int t = (threadIdx.x >= off) ? s[threadIdx.x - off] : 0;
    __syncthreads();
    s[threadIdx.x] += t;
    __syncthreads();
  }
  boff[threadIdx.x] = s[threadIdx.x] - v;          // exclusive
  if (threadIdx.x == 255) row_off[N] = s[255];     // total == E
}

__global__ void scan_final_kernel(const int* __restrict__ deg, const int* __restrict__ boff,
                                  int* __restrict__ row_off, int N) {
  __shared__ int s[256];
  int i = blockIdx.x * 256 + threadIdx.x;
  int v = (i < N) ? deg[i] : 0;
  s[threadIdx.x] = v;
  __syncthreads();
  for (int off = 1; off < 256; off <<= 1) {
    int t = (threadIdx.x >= off) ? s[threadIdx.x - off] : 0;
    __syncthreads();
    s[threadIdx.x] += t;
    __syncthreads();
  }
  if (i < N) row_off[i] = boff[blockIdx.x] + s[threadIdx.x] - v;
}

__global__ void fill_csr_kernel(const int* __restrict__ src, const int* __restrict__ dst,
                                const int* __restrict__ row_off, int* __restrict__ cursor,
                                int* __restrict__ col, int E) {
  int e = blockIdx.x * blockDim.x + threadIdx.x;
  if (e < E) {
    int d = dst[e];
    int pos = atomicAdd(&cursor[d], 1);
    col[row_off[d] + pos] = src[e];
  }
}

// out[i] = s_i * ( sum_{j in in(i)} s_j * z_j  +  s_i * z_i ),  z = h (+ gh[batch])
template <int CH, bool RES>
__global__ void aggregate_kernel(const float* __restrict__ h, const int* __restrict__ row_off,
                                 const int* __restrict__ col, const float* __restrict__ inv_s,
                                 const int* __restrict__ batch, const float* __restrict__ gh,
                                 float* __restrict__ out) {
  int i = blockIdx.x;
  int c = threadIdx.x;
  int e0 = row_off[i], e1 = row_off[i + 1];
  float si = inv_s[i];
  float zi = h[i * CH + c];
  if (RES) zi += gh[batch[i] * CH + c];
  float acc = si * zi;
  for (int e = e0; e < e1; ++e) {
    int j = col[e];
    float zj = h[j * CH + c];
    if (RES) zj += gh[batch[j] * CH + c];
    acc += inv_s[j] * zj;
  }
  out[i * CH + c] = si * acc;
}

// C[M,256] = A[M,K] @ B[K,256] + bias, optional relu. 64x64 tile, 4x4/thread.
#define GTM 64
#define GTN 64
#define GBK 32
__global__ __launch_bounds__(256) void gemm_kernel(const float* __restrict__ A,
                                                   const float* __restrict__ B,
                                                   const float* __restrict__ bias,
                                                   float* __restrict__ C, int M, int K, int relu) {
  const int NCOL = 256;
  __shared__ __align__(16) float As[GBK][GTM + 4];  // transposed: As[k][m], pad 4 keeps 16B align
  __shared__ __align__(16) float Bs[GBK][GTN];
  int row0 = blockIdx.x * GTM;
  int col0 = blockIdx.y * GTN;
  int tid = threadIdx.x;
  int tx = tid & 15, ty = tid >> 4;
  float acc[4][4] = {};
  for (int k0 = 0; k0 < K; k0 += GBK) {
    int lk = tid & 31, lr = tid >> 5;  // A: 32 k x 8 rows per pass
#pragma unroll
    for (int p = 0; p < 8; ++p) {
      int r = row0 + lr + p * 8;
      As[lk][lr + p * 8] = (r < M) ? A[(size_t)r * K + k0 + lk] : 0.0f;
    }
    int ln = tid & 63, lkb = tid >> 6;  // B: 64 n x 4 k per pass
#pragma unroll
    for (int p = 0; p < 8; ++p) {
      Bs[lkb + p * 4][ln] = B[(size_t)(k0 + lkb + p * 4) * NCOL + col0 + ln];
    }
    __syncthreads();
#pragma unroll
    for (int k = 0; k < GBK; ++k) {
      float4 a4 = *(const float4*)&As[k][ty * 4];
      float4 b4 = *(const float4*)&Bs[k][tx * 4];
      float av[4] = {a4.x, a4.y, a4.z, a4.w};
      float bv[4] = {b4.x, b4.y, b4.z, b4.w};
#pragma unroll
      for (int i = 0; i < 4; ++i)
#pragma unroll
        for (int j = 0; j < 4; ++j) acc[i][j] += av[i] * bv[j];
    }
    __syncthreads();
  }
#pragma unroll
  for (int i = 0; i < 4; ++i) {
    int r = row0 + ty * 4 + i;
    if (r < M) {
#pragma unroll
      for (int j = 0; j < 4; ++j) {
        int cc = col0 + tx * 4 + j;
        float v = acc[i][j] + bias[cc];
        if (relu) v = fmaxf(v, 0.0f);
        C[(size_t)r * NCOL + cc] = v;
      }
    }
  }
}

// batch is sorted: run-length accumulate per block, atomics only at run boundaries.
__global__ void pool_kernel(const float* __restrict__ h, const int* __restrict__ batch,
                            float* __restrict__ gmsum, float* __restrict__ cnt, int N, int chunk) {
  int start = blockIdx.x * chunk;
  int end = min(start + chunk, N);
  if (start >= end) return;
  int c = threadIdx.x;
  int g = batch[start];
  float acc = 0.0f;
  int run = 0;
  for (int n = start; n < end; ++n) {
    int bg = batch[n];
    if (bg != g) {
      atomicAdd(&gmsum[g * 256 + c], acc);
      if (c == 0) atomicAdd(&cnt[g], (float)run);
      acc = 0.0f;
      run = 0;
      g = bg;
    }
    acc += h[(size_t)n * 256 + c];
    run++;
  }
  atomicAdd(&gmsum[g * 256 + c], acc);
  if (c == 0) atomicAdd(&cnt[g], (float)run);
}

__global__ void final_kernel(const float* __restrict__ gmsum, const float* __restrict__ cnt,
                             const float* __restrict__ gh, const float* __restrict__ Wlin,
                             const float* __restrict__ blin, float* __restrict__ y,
                             float* __restrict__ gm_out, int G) {
  int g = blockIdx.x;
  int c = threadIdx.x;
  __shared__ float row[256];
  float v = gmsum[g * 256 + c] / fmaxf(cnt[g], 1.0f) + gh[g * 256 + c];
  gm_out[g * 256 + c] = v;
  row[c] = v;
  __syncthreads();
  if (c < 10) {
    float acc = blin[c];
    for (int k = 0; k < 256; ++k) acc += row[k] * Wlin[k * 10 + c];
    y[g * 10 + c] = acc;
  }
}

extern "C" void kernel_launch(void* const* d_in, const int* in_sizes, int n_in,
                              void* d_out, int out_size, void* d_ws, size_t ws_size,
                              hipStream_t stream) {
  const float* x = (const float*)d_in[0];
  const int* ei = (const int*)d_in[1];
  const int* batch = (const int*)d_in[2];
  const float* gh = (const float*)d_in[3];
  const float* W0 = (const float*)d_in[4];
  const float* b0 = (const float*)d_in[5];
  const float* Ws = (const float*)d_in[6];
  const float* bs = (const float*)d_in[7];
  const float* Wlin = (const float*)d_in[8];
  const float* blin = (const float*)d_in[9];
  float* out = (float*)d_out;

  const int N = in_sizes[2];
  const int E = in_sizes[1] / 2;
  const int G = in_sizes[3] / 256;
  const int H = 256, L = 3, C = 10;

  char* ws = (char*)d_ws;
  size_t off = 0;
  auto alloc = [&](size_t bytes) {
    void* p = ws + off;
    off += (bytes + 255) & ~(size_t)255;
    return p;
  };
  int* deg = (int*)alloc((size_t)N * 4);
  int* cursor = (int*)alloc((size_t)N * 4);
  int* row_off = (int*)alloc((size_t)(N + 1) * 4);
  int* bsum = (int*)alloc(256 * 4);
  int* boff = (int*)alloc(256 * 4);
  int* col = (int*)alloc((size_t)E * 4);
  float* inv_s = (float*)alloc((size_t)N * 4);
  float* cnt = (float*)alloc((size_t)G * 4);
  float* gmsum = (float*)alloc((size_t)G * H * 4);
  float* bufA = (float*)alloc((size_t)N * H * 4);  // h
  float* bufB = (float*)alloc((size_t)N * H * 4);  // aggregate output / gemm input

  const int* srcv = ei;
  const int* dstv = ei + E;

  hipMemsetAsync(deg, 0, (size_t)N * 4, stream);
  hipMemsetAsync(cursor, 0, (size_t)N * 4, stream);
  hipMemsetAsync(cnt, 0, (size_t)G * 4, stream);
  hipMemsetAsync(gmsum, 0, (size_t)G * H * 4, stream);

  int EB = (E + 255) / 256;
  int NB = (N + 255) / 256;
  count_deg_kernel<<<EB, 256, 0, stream>>>(dstv, deg, E);
  inv_s_kernel<<<NB, 256, 0, stream>>>(deg, inv_s, N);
  scan_partial_kernel<<<NB, 256, 0, stream>>>(deg, bsum, N);
  scan_block_kernel<<<1, 256, 0, stream>>>(bsum, boff, row_off, NB, N);
  scan_final_kernel<<<NB, 256, 0, stream>>>(deg, boff, row_off, N);
  fill_csr_kernel<<<EB, 256, 0, stream>>>(srcv, dstv, row_off, cursor, col, E);

  // Layer 0: aggregate x (128 ch), then h = agg @ W0 + b0  (no relu)
  aggregate_kernel<128, false><<<N, 128, 0, stream>>>(x, row_off, col, inv_s, batch, gh, bufB);
  {
    dim3 grid((N + GTM - 1) / GTM, 4);
    gemm_kernel<<<grid, 256, 0, stream>>>(bufB, W0, b0, bufA, N, 128, 0);
  }
  // Layers 1..3: agg(h + gh[batch]) -> relu(agg @ Ws + bs)
  for (int l = 0; l < L; ++l) {
    aggregate_kernel<256, true><<<N, 256, 0, stream>>>(bufA, row_off, col, inv_s, batch, gh, bufB);
    dim3 grid((N + GTM - 1) / GTM, 4);
    gemm_kernel<<<grid, 256, 0, stream>>>(bufB, Ws + (size_t)l * H * H, bs + (size_t)l * H, bufA,
                                          N, 256, 1);
  }

  int chunk = (N + 255) / 256;
  pool_kernel<<<256, 256, 0, stream>>>(bufA, batch, gmsum, cnt, N, chunk);
  final_kernel<<<G, 256, 0, stream>>>(gmsum, cnt, gh, Wlin, blin, out, out + (size_t)G * C, G);
}

// Round 2
// 579.844 us; speedup vs baseline: 2.3797x; 2.3797x over previous
//
#include <hip/hip_runtime.h>

// ---------------------------------------------------------------------------
// BlockGNN on MI355X, round 2: bf16 pipeline.
//   - u_j = s_j * (h_j + res_j) stored bf16 -> aggregation is a pure gather-sum
//   - out_i = s_i * (u_i + sum_j u_j)
//   - MFMA bf16 GEMM with fused bias/relu/residual/scale epilogue
// ---------------------------------------------------------------------------

typedef __bf16 bf16x8 __attribute__((ext_vector_type(8)));
typedef float f32x4 __attribute__((ext_vector_type(4)));

__device__ inline float bf2f(unsigned short u) {
  union { unsigned int i; float f; } v;
  v.i = (unsigned int)u << 16;
  return v.f;
}
__device__ inline unsigned short f2bf(float f) {
  union { unsigned int i; float f; } v;
  v.f = f;
  unsigned int i = v.i;
  return (unsigned short)((i + 0x7fffu + ((i >> 16) & 1u)) >> 16);  // RNE
}
__device__ inline unsigned int pack2(float a, float b) {
  return (unsigned int)f2bf(a) | ((unsigned int)f2bf(b) << 16);
}
__device__ inline void acc8(float* acc, uint4 r) {
  unsigned int w[4] = {r.x, r.y, r.z, r.w};
#pragma unroll
  for (int q = 0; q < 4; ++q) {
    acc[2 * q] += bf2f((unsigned short)(w[q] & 0xffffu));
    acc[2 * q + 1] += bf2f((unsigned short)(w[q] >> 16));
  }
}

// ----------------------------- CSR build -----------------------------------

__global__ void count_deg_kernel(const int* __restrict__ dst, int* __restrict__ deg, int E) {
  int e = blockIdx.x * blockDim.x + threadIdx.x;
  if (e < E) atomicAdd(&deg[dst[e]], 1);
}

__global__ void inv_s_kernel(const int* __restrict__ deg, float* __restrict__ inv_s, int N) {
  int i = blockIdx.x * blockDim.x + threadIdx.x;
  if (i < N) inv_s[i] = rsqrtf((float)(deg[i] + 1));  // +1 self loop
}

__global__ void scan_partial_kernel(const int* __restrict__ deg, int* __restrict__ bsum, int N) {
  __shared__ int s[256];
  int i = blockIdx.x * 256 + threadIdx.x;
  s[threadIdx.x] = (i < N) ? deg[i] : 0;
  __syncthreads();
  for (int off = 128; off > 0; off >>= 1) {
    if (threadIdx.x < off) s[threadIdx.x] += s[threadIdx.x + off];
    __syncthreads();
  }
  if (threadIdx.x == 0) bsum[blockIdx.x] = s[0];
}

__global__ void scan_block_kernel(const int* __restrict__ bsum, int* __restrict__ boff,
                                  int* __restrict__ row_off, int NB, int N) {
  __shared__ int s[256];
  int v = (threadIdx.x < NB) ? bsum[threadIdx.x] : 0;
  s[threadIdx.x] = v;
  __syncthreads();
  for (int off = 1; off < 256; off <<= 1) {
    int t = (threadIdx.x >= off) ? s[threadIdx.x - off] : 0;
    __syncthreads();
    s[threadIdx.x] += t;
    __syncthreads();
  }
  boff[threadIdx.x] = s[threadIdx.x] - v;
  if (threadIdx.x == 255) row_off[N] = s[255];
}

__global__ void scan_final_kernel(const int* __restrict__ deg, const int* __restrict__ boff,
                                  int* __restrict__ row_off, int N) {
  __shared__ int s[256];
  int i = blockIdx.x * 256 + threadIdx.x;
  int v = (i < N) ? deg[i] : 0;
  s[threadIdx.x] = v;
  __syncthreads();
  for (int off = 1; off < 256; off <<= 1) {
    int t = (threadIdx.x >= off) ? s[threadIdx.x - off] : 0;
    __syncthreads();
    s[threadIdx.x] += t;
    __syncthreads();
  }
  if (i < N) row_off[i] = boff[blockIdx.x] + s[threadIdx.x] - v;
}

__global__ void fill_csr_kernel(const int* __restrict__ src, const int* __restrict__ dst,
                                const int* __restrict__ row_off, int* __restrict__ cursor,
                                int* __restrict__ col, int E) {
  int e = blockIdx.x * blockDim.x + threadIdx.x;
  if (e < E) {
    int d = dst[e];
    int pos = atomicAdd(&cursor[d], 1);
    col[row_off[d] + pos] = src[e];
  }
}

// ----------------------------- prep ----------------------------------------

// u_x[i][c] = bf16( inv_s[i] * x[i][c] ),  CH = 128
__global__ void prep_ux_kernel(const float* __restrict__ x, const float* __restrict__ inv_s,
                               unsigned short* __restrict__ u, int total) {
  int idx = blockIdx.x * 256 + threadIdx.x;
  if (idx < total) {
    int i = idx >> 7;
    u[idx] = f2bf(inv_s[i] * x[idx]);
  }
}

// Wt[n][k] = bf16( W[k][n] );  W is [K][Ncol] row-major
__global__ void transpose_w_kernel(const float* __restrict__ W, unsigned short* __restrict__ Wt,
                                   int K, int Ncol) {
  int idx = blockIdx.x * 256 + threadIdx.x;
  if (idx < K * Ncol) {
    int k = idx / Ncol, n = idx - k * Ncol;
    Wt[n * K + k] = f2bf(W[idx]);
  }
}

// ----------------------------- aggregate ------------------------------------
// out_i = bf16( s_i * ( u_i + sum_{j in in(i)} u_j ) )
// One wave per node; LPR lanes (16B each) per row; EPW edges in flight.
template <int CH>
__global__ __launch_bounds__(256) void aggregate_kernel(
    const unsigned short* __restrict__ u, const int* __restrict__ row_off,
    const int* __restrict__ col, const float* __restrict__ inv_s,
    unsigned short* __restrict__ out, int N) {
  constexpr int LPR = CH / 8;    // lanes per row (each lane: 8 bf16 = 16B)
  constexpr int EPW = 64 / LPR;  // edges in parallel per wave
  int wave = threadIdx.x >> 6;
  int lane = threadIdx.x & 63;
  int i = blockIdx.x * 4 + wave;
  if (i >= N) return;
  int sub = lane / LPR;
  int c = lane % LPR;
  int e0 = row_off[i], e1 = row_off[i + 1];
  float acc[8] = {};
  int e = e0 + sub;
  for (; e + EPW < e1; e += 2 * EPW) {
    int j0 = col[e];
    int j1 = col[e + EPW];
    uint4 r0 = *(const uint4*)&u[(size_t)j0 * CH + c * 8];
    uint4 r1 = *(const uint4*)&u[(size_t)j1 * CH + c * 8];
    acc8(acc, r0);
    acc8(acc, r1);
  }
  if (e < e1) {
    int j = col[e];
    uint4 r = *(const uint4*)&u[(size_t)j * CH + c * 8];
    acc8(acc, r);
  }
#pragma unroll
  for (int k = 0; k < 8; ++k) {
    acc[k] += __shfl_down(acc[k], 32);
    if (EPW == 4) acc[k] += __shfl_down(acc[k], 16);
  }
  if (lane < LPR) {
    uint4 self = *(const uint4*)&u[(size_t)i * CH + c * 8];
    acc8(acc, self);
    float s = inv_s[i];
    uint4 o;
    o.x = pack2(s * acc[0], s * acc[1]);
    o.y = pack2(s * acc[2], s * acc[3]);
    o.z = pack2(s * acc[4], s * acc[5]);
    o.w = pack2(s * acc[6], s * acc[7]);
    *(uint4*)&out[(size_t)i * CH + c * 8] = o;
  }
}

// ----------------------------- MFMA GEMM ------------------------------------
// C[M,256] = A[M,K] @ W[K,256] (+bias, opt relu)
// WRITE_U: out = bf16( inv_s[r] * (C + gh[batch[r]]) )   (next layer's u)
// else:    out = bf16( C )                               (final h)
template <int K, bool RELU, bool WRITE_U>
__global__ __launch_bounds__(256) void gemm_kernel(
    const unsigned short* __restrict__ A,   // [M][K] bf16
    const unsigned short* __restrict__ Bt,  // [256][K] bf16 (W transposed)
    const float* __restrict__ bias,         // [256]
    const float* __restrict__ inv_s, const int* __restrict__ batch,
    const float* __restrict__ gh,           // [G][256]
    unsigned short* __restrict__ out,       // [M][256] bf16
    int M) {
  constexpr int BK = 32;
  constexpr int LDT = 40;  // padded stride in ushorts: 80 B (16B-aligned, bank-friendly)
  __shared__ unsigned short As[64 * LDT];
  __shared__ unsigned short Bs[256 * LDT];
  int tid = threadIdx.x;
  int wave = tid >> 6, lane = tid & 63;
  int quad = lane >> 4, l15 = lane & 15;
  int row0 = blockIdx.x * 64;
  f32x4 acc[4][4];
#pragma unroll
  for (int m = 0; m < 4; ++m)
#pragma unroll
    for (int n = 0; n < 4; ++n) acc[m][n] = (f32x4){0.f, 0.f, 0.f, 0.f};

  for (int k0 = 0; k0 < K; k0 += BK) {
    {  // stage A: 64 rows x 32 k
      int r = tid >> 2, kq = tid & 3;
      int gr = row0 + r;
      uint4 v = make_uint4(0u, 0u, 0u, 0u);
      if (gr < M) v = *(const uint4*)&A[(size_t)gr * K + k0 + kq * 8];
      *(uint4*)&As[r * LDT + kq * 8] = v;
    }
#pragma unroll
    for (int p = 0; p < 4; ++p) {  // stage B: 256 rows x 32 k
      int n = (tid >> 2) + p * 64, kq = tid & 3;
      *(uint4*)&Bs[n * LDT + kq * 8] = *(const uint4*)&Bt[(size_t)n * K + k0 + kq * 8];
    }
    __syncthreads();
    bf16x8 af[4], bfr[4];
#pragma unroll
    for (int m = 0; m < 4; ++m)
      af[m] = __builtin_bit_cast(bf16x8, *(const uint4*)&As[(m * 16 + l15) * LDT + quad * 8]);
#pragma unroll
    for (int n = 0; n < 4; ++n)
      bfr[n] = __builtin_bit_cast(bf16x8,
                                  *(const uint4*)&Bs[(wave * 64 + n * 16 + l15) * LDT + quad * 8]);
#pragma unroll
    for (int m = 0; m < 4; ++m)
#pragma unroll
      for (int n = 0; n < 4; ++n)
        acc[m][n] = __builtin_amdgcn_mfma_f32_16x16x32_bf16(af[m], bfr[n], acc[m][n], 0, 0, 0);
    __syncthreads();
  }
  // epilogue: C/D map col=lane&15, row=(lane>>4)*4+reg
#pragma unroll
  for (int m = 0; m < 4; ++m) {
#pragma unroll
    for (int r = 0; r < 4; ++r) {
      int gr = row0 + m * 16 + quad * 4 + r;
      if (gr >= M) continue;
      float sv = 1.0f;
      int bofs = 0;
      if (WRITE_U) {
        sv = inv_s[gr];
        bofs = batch[gr] * 256;
      }
#pragma unroll
      for (int n = 0; n < 4; ++n) {
        int cc = wave * 64 + n * 16 + l15;
        float v = acc[m][n][r] + bias[cc];
        if (RELU) v = fmaxf(v, 0.f);
        if (WRITE_U) v = sv * (v + gh[bofs + cc]);
        out[(size_t)gr * 256 + cc] = f2bf(v);
      }
    }
  }
}

// ----------------------------- pool + final ---------------------------------

__global__ void pool_kernel(const unsigned short* __restrict__ h, const int* __restrict__ batch,
                            float* __restrict__ gmsum, float* __restrict__ cnt, int N, int chunk) {
  int start = blockIdx.x * chunk;
  int end = min(start + chunk, N);
  if (start >= end) return;
  int c = threadIdx.x;
  int g = batch[start];
  float acc = 0.0f;
  int run = 0;
  for (int n = start; n < end; ++n) {
    int bg = batch[n];
    if (bg != g) {
      atomicAdd(&gmsum[g * 256 + c], acc);
      if (c == 0) atomicAdd(&cnt[g], (float)run);
      acc = 0.0f;
      run = 0;
      g = bg;
    }
    acc += bf2f(h[(size_t)n * 256 + c]);
    run++;
  }
  atomicAdd(&gmsum[g * 256 + c], acc);
  if (c == 0) atomicAdd(&cnt[g], (float)run);
}

__global__ void final_kernel(const float* __restrict__ gmsum, const float* __restrict__ cnt,
                             const float* __restrict__ gh, const float* __restrict__ Wlin,
                             const float* __restrict__ blin, float* __restrict__ y,
                             float* __restrict__ gm_out, int G) {
  int g = blockIdx.x;
  int c = threadIdx.x;
  __shared__ float row[256];
  float v = gmsum[g * 256 + c] / fmaxf(cnt[g], 1.0f) + gh[g * 256 + c];
  gm_out[g * 256 + c] = v;
  row[c] = v;
  __syncthreads();
  if (c < 10) {
    float acc = blin[c];
    for (int k = 0; k < 256; ++k) acc += row[k] * Wlin[k * 10 + c];
    y[g * 10 + c] = acc;
  }
}

// ----------------------------- launch ----------------------------------------

extern "C" void kernel_launch(void* const* d_in, const int* in_sizes, int n_in,
                              void* d_out, int out_size, void* d_ws, size_t ws_size,
                              hipStream_t stream) {
  const float* x = (const float*)d_in[0];
  const int* ei = (const int*)d_in[1];
  const int* batch = (const int*)d_in[2];
  const float* gh = (const float*)d_in[3];
  const float* W0 = (const float*)d_in[4];
  const float* b0 = (const float*)d_in[5];
  const float* Ws = (const float*)d_in[6];
  const float* bs = (const float*)d_in[7];
  const float* Wlin = (const float*)d_in[8];
  const float* blin = (const float*)d_in[9];
  float* out = (float*)d_out;

  const int N = in_sizes[2];
  const int E = in_sizes[1] / 2;
  const int G = in_sizes[3] / 256;
  const int H = 256, L = 3, C = 10, F = 128;

  char* ws = (char*)d_ws;
  size_t off = 0;
  auto alloc = [&](size_t bytes) {
    void* p = ws + off;
    off += (bytes + 255) & ~(size_t)255;
    return p;
  };
  int* deg = (int*)alloc((size_t)N * 4);
  int* cursor = (int*)alloc((size_t)N * 4);
  int* row_off = (int*)alloc((size_t)(N + 1) * 4);
  int* bsum = (int*)alloc(256 * 4);
  int* boff = (int*)alloc(256 * 4);
  int* col = (int*)alloc((size_t)E * 4);
  float* inv_s = (float*)alloc((size_t)N * 4);
  float* cnt = (float*)alloc((size_t)G * 4);
  float* gmsum = (float*)alloc((size_t)G * H * 4);
  unsigned short* u_x = (unsigned short*)alloc((size_t)N * F * 2);   // s*x
  unsigned short* uA = (unsigned short*)alloc((size_t)N * H * 2);    // s*(h+res)
  unsigned short* aggA = (unsigned short*)alloc((size_t)N * H * 2);  // aggregate out / GEMM A
  unsigned short* hfin = (unsigned short*)alloc((size_t)N * H * 2);  // final h
  unsigned short* Wt0 = (unsigned short*)alloc((size_t)F * H * 2);   // [256][128]
  unsigned short* WtS = (unsigned short*)alloc((size_t)L * H * H * 2);

  const int* srcv = ei;
  const int* dstv = ei + E;

  hipMemsetAsync(deg, 0, (size_t)N * 4, stream);
  hipMemsetAsync(cursor, 0, (size_t)N * 4, stream);
  hipMemsetAsync(cnt, 0, (size_t)G * 4, stream);
  hipMemsetAsync(gmsum, 0, (size_t)G * H * 4, stream);

  int EB = (E + 255) / 256;
  int NB = (N + 255) / 256;
  count_deg_kernel<<<EB, 256, 0, stream>>>(dstv, deg, E);
  inv_s_kernel<<<NB, 256, 0, stream>>>(deg, inv_s, N);
  scan_partial_kernel<<<NB, 256, 0, stream>>>(deg, bsum, N);
  scan_block_kernel<<<1, 256, 0, stream>>>(bsum, boff, row_off, NB, N);
  scan_final_kernel<<<NB, 256, 0, stream>>>(deg, boff, row_off, N);
  fill_csr_kernel<<<EB, 256, 0, stream>>>(srcv, dstv, row_off, cursor, col, E);

  prep_ux_kernel<<<(N * F + 255) / 256, 256, 0, stream>>>(x, inv_s, u_x, N * F);
  transpose_w_kernel<<<(F * H + 255) / 256, 256, 0, stream>>>(W0, Wt0, F, H);
  for (int l = 0; l < L; ++l)
    transpose_w_kernel<<<(H * H + 255) / 256, 256, 0, stream>>>(Ws + (size_t)l * H * H,
                                                                WtS + (size_t)l * H * H, H, H);

  int AGG_GRID = (N + 3) / 4;
  int GEMM_GRID = (N + 63) / 64;

  // layer 0: agg(u_x) -> GEMM K=128 (no relu) -> uA = s*(h0+res)
  aggregate_kernel<128><<<AGG_GRID, 256, 0, stream>>>(u_x, row_off, col, inv_s, aggA, N);
  gemm_kernel<128, false, true><<<GEMM_GRID, 256, 0, stream>>>(aggA, Wt0, b0, inv_s, batch, gh,
                                                               uA, N);
  // layers 1..2: agg(uA) -> GEMM relu -> uA
  for (int l = 0; l < 2; ++l) {
    aggregate_kernel<256><<<AGG_GRID, 256, 0, stream>>>(uA, row_off, col, inv_s, aggA, N);
    gemm_kernel<256, true, true><<<GEMM_GRID, 256, 0, stream>>>(
        aggA, WtS + (size_t)l * H * H, bs + (size_t)l * H, inv_s, batch, gh, uA, N);
  }
  // layer 3: agg(uA) -> GEMM relu -> h (bf16)
  aggregate_kernel<256><<<AGG_GRID, 256, 0, stream>>>(uA, row_off, col, inv_s, aggA, N);
  gemm_kernel<256, true, false><<<GEMM_GRID, 256, 0, stream>>>(
      aggA, WtS + (size_t)2 * H * H, bs + (size_t)2 * H, inv_s, batch, gh, hfin, N);

  int chunk = (N + 255) / 256;
  pool_kernel<<<256, 256, 0, stream>>>(hfin, batch, gmsum, cnt, N, chunk);
  final_kernel<<<G, 256, 0, stream>>>(gmsum, cnt, gh, Wlin, blin, out, out + (size_t)G * C, G);
}